// Round 1
// baseline (1068.791 us; speedup 1.0000x reference)
//
#include <hip/hip_runtime.h>
#include <hip/hip_bf16.h>

#define BB 2
#define NN 256
#define DD 128
#define TDD 64
#define LL 4
#define NGROUP 32
#define NROWS (BB*NN*NN)      // 131072 edge rows
#define LDS_STR 68            // padded LDS stride (dwords), 16B aligned, bank-spread

#define LOG1E4 9.210340371976184f
#define TWO_PI 6.283185307179586f

// ---------------- generic 64row x 128col tile GEMM inner loop ----------------
// AT: __shared__ float[128*LDS_STR], transposed A tile: AT[k*LDS_STR + row]
// WPTR: const float* row-major W[k*128 + c]
// tx = tid&31 (cols 4*tx..4*tx+3), ty = tid>>5 (rows 8*ty..8*ty+7)
#define TILE_GEMM(AT, WPTR, ACC) do {                                          \
  _Pragma("unroll 4")                                                          \
  for (int k = 0; k < 128; ++k) {                                              \
    const float4 w4 = *reinterpret_cast<const float4*>((WPTR) + k*128 + tx*4); \
    const float4 a0 = *reinterpret_cast<const float4*>(&(AT)[k*LDS_STR + ty*8]);     \
    const float4 a1 = *reinterpret_cast<const float4*>(&(AT)[k*LDS_STR + ty*8 + 4]); \
    const float av[8] = {a0.x,a0.y,a0.z,a0.w,a1.x,a1.y,a1.z,a1.w};             \
    const float wv[4] = {w4.x,w4.y,w4.z,w4.w};                                 \
    _Pragma("unroll") for (int r = 0; r < 8; ++r)                              \
      _Pragma("unroll") for (int c = 0; c < 4; ++c)                            \
        ACC[r][c] += av[r]*wv[c];                                              \
  }                                                                            \
} while (0)

__device__ __forceinline__ float sigmoidf_(float x) {
  return 1.f / (1.f + __expf(-x));
}

// ---------------- time embedding pipeline -> tproj[L][B][D] ----------------
__global__ __launch_bounds__(128) void k_time(
    const float* __restrict__ t,
    const float* __restrict__ te1_W, const float* __restrict__ te1_b,
    const float* __restrict__ te2_W, const float* __restrict__ te2_b,
    const float* __restrict__ tl_W,  const float* __restrict__ tl_b,
    float* __restrict__ tproj) {
  __shared__ float temb[128], h1[64], rt[64];
  int tid = threadIdx.x;
  for (int b = 0; b < BB; ++b) {
    float tv = t[b];
    {
      int j = tid & 63;
      float f = expf(-LOG1E4 * (float)j / 64.f);
      float a = tv * f;
      temb[tid] = (tid < 64) ? cosf(a) : sinf(a);
    }
    __syncthreads();
    if (tid < 64) {
      float acc = te1_b[tid];
      for (int k = 0; k < 128; ++k) acc += temb[k] * te1_W[k*64 + tid];
      h1[tid] = fmaxf(acc, 0.f);
    }
    __syncthreads();
    if (tid < 64) {
      float acc = te2_b[tid];
      for (int k = 0; k < 64; ++k) acc += h1[k] * te2_W[k*64 + tid];
      rt[tid] = fmaxf(acc, 0.f);   // relu(te)
    }
    __syncthreads();
    for (int i = 0; i < LL; ++i) {
      float acc = tl_b[i*128 + tid];
      for (int k = 0; k < 64; ++k) acc += rt[k] * tl_W[(i*64 + k)*128 + tid];
      tproj[(i*BB + b)*128 + tid] = acc;
    }
    __syncthreads();
  }
}

// ---------------- node pos-embed + node_W GEMM -> x (512 x 128) ----------------
__global__ __launch_bounds__(256) void k_node_embed(
    const float* __restrict__ coords, const float* __restrict__ W,
    const float* __restrict__ bias, float* __restrict__ x_out) {
  __shared__ float at[128*LDS_STR];
  int tid = threadIdx.x;
  int row = tid >> 2, part = tid & 3;
  int R = blockIdx.x*64 + row;
  float cy = coords[R*2 + 0], cx = coords[R*2 + 1];
#pragma unroll
  for (int q = 0; q < 32; ++q) {
    int c = part*32 + q;
    int k = (c < 64) ? c : c - 64;
    float v = (c < 64) ? cy : cx;
    int m = k >> 1;
    float inv = expf(-LOG1E4 * (float)m / 32.f);   // 10000^(-m/32), npf=64
    float a = v * TWO_PI * inv;
    at[c*LDS_STR + row] = (k & 1) ? cosf(a) : sinf(a);
  }
  __syncthreads();
  int tx = tid & 31, ty = tid >> 5;
  float acc[8][4] = {};
  TILE_GEMM(at, W, acc);
  float4 bb4 = *reinterpret_cast<const float4*>(bias + tx*4);
#pragma unroll
  for (int r = 0; r < 8; ++r) {
    int R2 = blockIdx.x*64 + ty*8 + r;
    float4 o = {acc[r][0]+bb4.x, acc[r][1]+bb4.y, acc[r][2]+bb4.z, acc[r][3]+bb4.w};
    *reinterpret_cast<float4*>(x_out + (size_t)R2*128 + tx*4) = o;
  }
}

// ---------------- edge pos-embed + edge_W GEMM -> e (131072 x 128) ----------------
__global__ __launch_bounds__(256) void k_edge_embed(
    const float* __restrict__ adj, const float* __restrict__ W,
    const float* __restrict__ bias, float* __restrict__ e_out) {
  __shared__ float at[128*LDS_STR];
  int tid = threadIdx.x;
  int row = tid >> 2, part = tid & 3;
  size_t R = (size_t)blockIdx.x*64 + row;
  float v = adj[R];
#pragma unroll
  for (int q = 0; q < 32; ++q) {
    int k = part*32 + q;
    int m = k >> 1;
    float inv = expf(-LOG1E4 * (float)m / 64.f);   // 10000^(-m/64), npf=128
    float a = v * inv;
    at[k*LDS_STR + row] = (k & 1) ? cosf(a) : sinf(a);
  }
  __syncthreads();
  int tx = tid & 31, ty = tid >> 5;
  float acc[8][4] = {};
  TILE_GEMM(at, W, acc);
  float4 bb4 = *reinterpret_cast<const float4*>(bias + tx*4);
#pragma unroll
  for (int r = 0; r < 8; ++r) {
    size_t R2 = (size_t)blockIdx.x*64 + ty*8 + r;
    float4 o = {acc[r][0]+bb4.x, acc[r][1]+bb4.y, acc[r][2]+bb4.z, acc[r][3]+bb4.w};
    *reinterpret_cast<float4*>(e_out + R2*128 + tx*4) = o;
  }
}

// ---------------- per-layer node linears: Uh,Vh,Ax,Bx (512 rows) ----------------
__global__ __launch_bounds__(128) void k_node4(
    const float* __restrict__ x,
    const float* __restrict__ UW, const float* __restrict__ Ub,
    const float* __restrict__ VW, const float* __restrict__ Vb,
    const float* __restrict__ AW, const float* __restrict__ Ab,
    const float* __restrict__ BW, const float* __restrict__ Bb,
    float* __restrict__ Uh, float* __restrict__ Vh,
    float* __restrict__ Axo, float* __restrict__ Bxo) {
  __shared__ float xr[128];
  int R = blockIdx.x, d = threadIdx.x;
  xr[d] = x[(size_t)R*128 + d];
  __syncthreads();
  float au = Ub[d], av = Vb[d], aa = Ab[d], ab = Bb[d];
  for (int k = 0; k < 128; ++k) {
    float xv = xr[k];
    au += xv * UW[k*128 + d];
    av += xv * VW[k*128 + d];
    aa += xv * AW[k*128 + d];
    ab += xv * BW[k*128 + d];
  }
  Uh[(size_t)R*128 + d] = au;
  Vh[(size_t)R*128 + d] = av;
  Axo[(size_t)R*128 + d] = aa;
  Bxo[(size_t)R*128 + d] = ab;
}

// ---------------- gate GEMM: gate = e @ C_W + C_b + Ax[b,i] + Bx[b,j] ----------------
__global__ __launch_bounds__(256) void k_gate(
    const float* __restrict__ e, const float* __restrict__ CW,
    const float* __restrict__ Cb, const float* __restrict__ Ax,
    const float* __restrict__ Bx, float* __restrict__ gate) {
  __shared__ float at[128*LDS_STR];
  int tid = threadIdx.x;
  int row = tid >> 2, part = tid & 3;
  size_t R = (size_t)blockIdx.x*64 + row;
  const float4* erow = reinterpret_cast<const float4*>(e + R*128 + part*32);
#pragma unroll
  for (int q = 0; q < 8; ++q) {
    float4 f = erow[q];
    int k = part*32 + q*4;
    at[(k+0)*LDS_STR + row] = f.x;
    at[(k+1)*LDS_STR + row] = f.y;
    at[(k+2)*LDS_STR + row] = f.z;
    at[(k+3)*LDS_STR + row] = f.w;
  }
  __syncthreads();
  int tx = tid & 31, ty = tid >> 5;
  float acc[8][4] = {};
  TILE_GEMM(at, CW, acc);
  size_t base = (size_t)blockIdx.x*64;
  size_t bi = base >> 8;          // b*256+i, same for whole block
  size_t b  = base >> 16;
  float4 cb4 = *reinterpret_cast<const float4*>(Cb + tx*4);
  float4 ax4 = *reinterpret_cast<const float4*>(Ax + bi*128 + tx*4);
#pragma unroll
  for (int r = 0; r < 8; ++r) {
    size_t R2 = base + ty*8 + r;
    size_t j = R2 & 255;
    float4 bx4 = *reinterpret_cast<const float4*>(Bx + (b*256 + j)*128 + tx*4);
    float4 o = {acc[r][0]+cb4.x+ax4.x+bx4.x, acc[r][1]+cb4.y+ax4.y+bx4.y,
                acc[r][2]+cb4.z+ax4.z+bx4.z, acc[r][3]+cb4.w+ax4.w+bx4.w};
    *reinterpret_cast<float4*>(gate + R2*128 + tx*4) = o;
  }
}

// ---------------- agg + h_new + x update (per (b,i) row) ----------------
__global__ __launch_bounds__(128) void k_agg(
    const float* __restrict__ gate, const float* __restrict__ Vh,
    const float* __restrict__ Uh, const float* __restrict__ lnh_s,
    const float* __restrict__ lnh_b, float* __restrict__ x) {
  int bi = blockIdx.x;            // b*256+i
  size_t b = bi >> 8;
  int d = threadIdx.x;
  float acc = 0.f;
  size_t gbase = (size_t)bi*NN*128 + d;
  size_t vbase = b*NN*128 + d;
  for (int j = 0; j < NN; ++j) {
    float g = gate[gbase + (size_t)j*128];
    float v = Vh[vbase + (size_t)j*128];
    acc += v * sigmoidf_(g);
  }
  float u = Uh[(size_t)bi*128 + d] + acc;
  float s = u, s2 = u*u;
#pragma unroll
  for (int m = 1; m <= 32; m <<= 1) { s += __shfl_xor(s, m); s2 += __shfl_xor(s2, m); }
  __shared__ float red[4];
  int wid = d >> 6;
  if ((d & 63) == 0) { red[wid] = s; red[2 + wid] = s2; }
  __syncthreads();
  s = red[0] + red[1]; s2 = red[2] + red[3];
  float mean = s / 128.f;
  float var = s2 / 128.f - mean*mean;
  float rs = rsqrtf(var + 1e-5f);
  float h = fmaxf((u - mean)*rs*lnh_s[d] + lnh_b[d], 0.f);
  x[(size_t)bi*128 + d] += h;
}

// -------- edge update: e += silu(ln(relu(ln(gate))+tproj)) @ plo_W + plo_b --------
__global__ __launch_bounds__(256) void k_edge_upd(
    const float* __restrict__ gate,
    const float* __restrict__ lne_s, const float* __restrict__ lne_b,
    const float* __restrict__ tproj_i,
    const float* __restrict__ plo_s, const float* __restrict__ plo_bln,
    const float* __restrict__ ploW, const float* __restrict__ plob,
    float* __restrict__ e) {
  __shared__ float at[128*LDS_STR];
  int tid = threadIdx.x;
  int row = tid >> 2, part = tid & 3;
  size_t R = (size_t)blockIdx.x*64 + row;
  size_t b = R >> 16;
  float v[32];
  const float4* grow = reinterpret_cast<const float4*>(gate + R*128 + part*32);
  float s = 0.f, s2 = 0.f;
#pragma unroll
  for (int q = 0; q < 8; ++q) {
    float4 f = grow[q];
    v[q*4+0] = f.x; v[q*4+1] = f.y; v[q*4+2] = f.z; v[q*4+3] = f.w;
    s += f.x + f.y + f.z + f.w;
    s2 += f.x*f.x + f.y*f.y + f.z*f.z + f.w*f.w;
  }
  s += __shfl_xor(s, 1);  s += __shfl_xor(s, 2);
  s2 += __shfl_xor(s2, 1); s2 += __shfl_xor(s2, 2);
  float mean = s / 128.f;
  float rs = rsqrtf(s2/128.f - mean*mean + 1e-5f);
  float s3 = 0.f, s4 = 0.f;
#pragma unroll
  for (int q = 0; q < 32; ++q) {
    int c = part*32 + q;
    float tt = fmaxf((v[q] - mean)*rs*lne_s[c] + lne_b[c], 0.f) + tproj_i[b*128 + c];
    v[q] = tt;
    s3 += tt; s4 += tt*tt;
  }
  s3 += __shfl_xor(s3, 1);  s3 += __shfl_xor(s3, 2);
  s4 += __shfl_xor(s4, 1);  s4 += __shfl_xor(s4, 2);
  float mean2 = s3 / 128.f;
  float rs2 = rsqrtf(s4/128.f - mean2*mean2 + 1e-5f);
#pragma unroll
  for (int q = 0; q < 32; ++q) {
    int c = part*32 + q;
    float tt = (v[q] - mean2)*rs2*plo_s[c] + plo_bln[c];
    at[c*LDS_STR + row] = tt * sigmoidf_(tt);   // silu
  }
  __syncthreads();
  int tx = tid & 31, ty = tid >> 5;
  float acc[8][4] = {};
  TILE_GEMM(at, ploW, acc);
  float4 pb4 = *reinterpret_cast<const float4*>(plob + tx*4);
#pragma unroll
  for (int r = 0; r < 8; ++r) {
    size_t R2 = (size_t)blockIdx.x*64 + ty*8 + r;
    float4 ev = *reinterpret_cast<const float4*>(e + R2*128 + tx*4);
    float4 o = {ev.x+acc[r][0]+pb4.x, ev.y+acc[r][1]+pb4.y,
                ev.z+acc[r][2]+pb4.z, ev.w+acc[r][3]+pb4.w};
    *reinterpret_cast<float4*>(e + R2*128 + tx*4) = o;
  }
}

// ---------------- groupnorm stats: per (b,g) mean & rsqrt(var+eps) ----------------
__global__ __launch_bounds__(256) void k_gnstats(
    const float* __restrict__ e, float* __restrict__ stats) {
  int b = blockIdx.x >> 5, g = blockIdx.x & 31;
  int tid = threadIdx.x;
  float s = 0.f, s2 = 0.f;
  for (int p = tid; p < NN*NN; p += 256) {
    float4 f = *reinterpret_cast<const float4*>(e + ((size_t)b*NN*NN + p)*128 + g*4);
    s += f.x + f.y + f.z + f.w;
    s2 += f.x*f.x + f.y*f.y + f.z*f.z + f.w*f.w;
  }
#pragma unroll
  for (int m = 1; m <= 32; m <<= 1) { s += __shfl_xor(s, m); s2 += __shfl_xor(s2, m); }
  __shared__ float ra[4], rb[4];
  int wid = tid >> 6;
  if ((tid & 63) == 0) { ra[wid] = s; rb[wid] = s2; }
  __syncthreads();
  if (tid == 0) {
    float S = ra[0]+ra[1]+ra[2]+ra[3];
    float S2 = rb[0]+rb[1]+rb[2]+rb[3];
    const float cnt = (float)(NN*NN*4);
    float mean = S / cnt;
    float var = S2 / cnt - mean*mean;
    stats[(b*NGROUP + g)*2 + 0] = mean;
    stats[(b*NGROUP + g)*2 + 1] = rsqrtf(var + 1e-5f);
  }
}

// ---------------- final: out = relu(gn(e)) . conv_W + conv_b ----------------
__global__ __launch_bounds__(256) void k_out(
    const float* __restrict__ e, const float* __restrict__ stats,
    const float* __restrict__ gn_s, const float* __restrict__ gn_b,
    const float* __restrict__ convW, const float* __restrict__ convb,
    float* __restrict__ out) {
  int tid = threadIdx.x;
  int row = tid >> 2, part = tid & 3;
  size_t R = (size_t)blockIdx.x*64 + row;
  size_t b = R >> 16;
  float acc = 0.f;
  const float4* er = reinterpret_cast<const float4*>(e + R*128 + part*32);
#pragma unroll
  for (int q = 0; q < 8; ++q) {
    float4 f = er[q];
    float fv[4] = {f.x, f.y, f.z, f.w};
#pragma unroll
    for (int l = 0; l < 4; ++l) {
      int c = part*32 + q*4 + l;
      int g = c >> 2;
      float mean = stats[(b*NGROUP + g)*2 + 0];
      float rs   = stats[(b*NGROUP + g)*2 + 1];
      float t = (fv[l] - mean)*rs*gn_s[c] + gn_b[c];
      acc += fmaxf(t, 0.f) * convW[c];
    }
  }
  acc += __shfl_xor(acc, 1);
  acc += __shfl_xor(acc, 2);
  if (part == 0) out[R] = acc + convb[0];
}

extern "C" void kernel_launch(void* const* d_in, const int* in_sizes, int n_in,
                              void* d_out, int out_size, void* d_ws, size_t ws_size,
                              hipStream_t stream) {
  const float* coords  = (const float*)d_in[0];
  const float* adj_t   = (const float*)d_in[1];
  const float* t       = (const float*)d_in[2];
  const float* node_W  = (const float*)d_in[3];
  const float* node_b  = (const float*)d_in[4];
  const float* edge_W  = (const float*)d_in[5];
  const float* edge_b  = (const float*)d_in[6];
  const float* te1_W   = (const float*)d_in[7];
  const float* te1_b   = (const float*)d_in[8];
  const float* te2_W   = (const float*)d_in[9];
  const float* te2_b   = (const float*)d_in[10];
  const float* A_W     = (const float*)d_in[11];
  const float* A_b     = (const float*)d_in[12];
  const float* B_W     = (const float*)d_in[13];
  const float* B_b     = (const float*)d_in[14];
  const float* C_W     = (const float*)d_in[15];
  const float* C_b     = (const float*)d_in[16];
  const float* U_W     = (const float*)d_in[17];
  const float* U_b     = (const float*)d_in[18];
  const float* V_W     = (const float*)d_in[19];
  const float* V_b     = (const float*)d_in[20];
  const float* lnh_s   = (const float*)d_in[21];
  const float* lnh_b   = (const float*)d_in[22];
  const float* lne_s   = (const float*)d_in[23];
  const float* lne_b   = (const float*)d_in[24];
  const float* tl_W    = (const float*)d_in[25];
  const float* tl_b    = (const float*)d_in[26];
  const float* plo_ln_s= (const float*)d_in[27];
  const float* plo_ln_b= (const float*)d_in[28];
  const float* plo_W   = (const float*)d_in[29];
  const float* plo_b   = (const float*)d_in[30];
  const float* gn_s    = (const float*)d_in[31];
  const float* gn_b    = (const float*)d_in[32];
  const float* conv_W  = (const float*)d_in[33];
  const float* conv_b  = (const float*)d_in[34];

  float* ws   = (float*)d_ws;
  float* e    = ws;                        // 16777216
  float* gate = e + (size_t)NROWS*128;     // 16777216
  float* x    = gate + (size_t)NROWS*128;  // 65536
  float* Uh   = x + 65536;
  float* Vh   = Uh + 65536;
  float* Ax   = Vh + 65536;
  float* Bx   = Ax + 65536;
  float* tproj= Bx + 65536;                // L*B*128 = 1024
  float* stats= tproj + 1024;              // B*32*2 = 128

  k_time<<<1, 128, 0, stream>>>(t, te1_W, te1_b, te2_W, te2_b, tl_W, tl_b, tproj);
  k_node_embed<<<8, 256, 0, stream>>>(coords, node_W, node_b, x);
  k_edge_embed<<<NROWS/64, 256, 0, stream>>>(adj_t, edge_W, edge_b, e);

  for (int i = 0; i < LL; ++i) {
    k_node4<<<BB*NN, 128, 0, stream>>>(x,
        U_W + (size_t)i*16384, U_b + i*128,
        V_W + (size_t)i*16384, V_b + i*128,
        A_W + (size_t)i*16384, A_b + i*128,
        B_W + (size_t)i*16384, B_b + i*128,
        Uh, Vh, Ax, Bx);
    k_gate<<<NROWS/64, 256, 0, stream>>>(e, C_W + (size_t)i*16384, C_b + i*128,
                                         Ax, Bx, gate);
    k_agg<<<BB*NN, 128, 0, stream>>>(gate, Vh, Uh, lnh_s + i*128, lnh_b + i*128, x);
    k_edge_upd<<<NROWS/64, 256, 0, stream>>>(gate,
        lne_s + i*128, lne_b + i*128, tproj + i*BB*128,
        plo_ln_s + i*128, plo_ln_b + i*128,
        plo_W + (size_t)i*16384, plo_b + i*128, e);
  }

  k_gnstats<<<BB*NGROUP, 256, 0, stream>>>(e, stats);
  k_out<<<NROWS/64, 256, 0, stream>>>(e, stats, gn_s, gn_b, conv_W, conv_b,
                                      (float*)d_out);
}